// Round 6
// baseline (267.737 us; speedup 1.0000x reference)
//
#include <hip/hip_runtime.h>
#include <hip/hip_bf16.h>

#define NF   1024   // N features
#define NHID 256    // H hidden
#define NJ   1280   // N+H keys
#define ED   64     // E = HD = 64
#define BATCH 8192

#define K2E   2.8853900817779268f   // 2*log2(e)
#define LOG2E 1.4426950408889634f

__device__ __forceinline__ float exp2_fast(float x) {
    float r;
    asm volatile("v_exp_f32 %0, %1" : "=v"(r) : "v"(x));
    return r;
}

// ---- Kernel 1: Ap[i][e] = K2E*(feat@W1) ; BvT[e][j] = K2E*((full@W2)[j][e] + bw[e]) ----
__global__ __launch_bounds__(256) void prep_kernel(
    const float* __restrict__ feat, const float* __restrict__ hid,
    const float* __restrict__ Ww, const float* __restrict__ bw,
    float* __restrict__ Ap, float* __restrict__ BvT)
{
    __shared__ __align__(16) float in_s[64][64];
    __shared__ __align__(16) float tout[64][65];
    const int tid = threadIdx.x;
    const int b   = blockIdx.x;
    const bool isA = (b < 16);
    const int e  = tid & 63;
    const int wv = tid >> 6;

    const float* W = isA ? Ww : (Ww + 4096);
    float wcol[64];
    #pragma unroll
    for (int k = 0; k < 64; k++) wcol[k] = W[k * 64 + e];
    const float bias = isA ? 0.f : bw[e];

    const int bb = isA ? b : (b - 16);
    const float* src = isA ? (feat + (size_t)bb * 4096)
                     : (bb < 16 ? (feat + (size_t)bb * 4096)
                                : (hid + (size_t)(bb - 16) * 4096));
    #pragma unroll
    for (int s = 0; s < 4; s++)
        ((float4*)&in_s[0][0])[tid + s * 256] = ((const float4*)src)[tid + s * 256];
    __syncthreads();

    float acc[16];
    #pragma unroll
    for (int r = 0; r < 16; r++) acc[r] = bias;
    for (int k4 = 0; k4 < 64; k4 += 4) {
        #pragma unroll
        for (int r = 0; r < 16; r++) {
            float4 iv = *(const float4*)&in_s[wv * 16 + r][k4];
            acc[r] += iv.x*wcol[k4+0] + iv.y*wcol[k4+1] + iv.z*wcol[k4+2] + iv.w*wcol[k4+3];
        }
    }

    if (isA) {
        #pragma unroll
        for (int r = 0; r < 16; r++)
            Ap[(size_t)(b * 64 + wv * 16 + r) * 64 + e] = acc[r] * K2E;
    } else {
        #pragma unroll
        for (int r = 0; r < 16; r++) tout[wv * 16 + r][e] = acc[r] * K2E;
        __syncthreads();
        const int j0 = bb * 64;
        #pragma unroll
        for (int q = 0; q < 4; q++) {
            float4 v;
            v.x = tout[wv * 16 + q * 4 + 0][e];
            v.y = tout[wv * 16 + q * 4 + 1][e];
            v.z = tout[wv * 16 + q * 4 + 2][e];
            v.w = tout[wv * 16 + q * 4 + 3][e];
            *(float4*)&BvT[(size_t)e * NJ + j0 + wv * 16 + q * 4] = v;
        }
    }
}

// ---- Kernel 2 (S): masked exp-scores.  512 blocks = 256 i-quads x 2 j-halves, 320 thr ----
// sc[i][j] = mask ? exp(score(i,j)) : 0.  score via Swu - 2*sum wu/(exp(2x)+1), all in exp2 domain.
__global__ __launch_bounds__(320) void score_kernel(
    const float* __restrict__ Wu, const float* __restrict__ Ap,
    const float* __restrict__ BvT, const void* __restrict__ maskp,
    float* __restrict__ sc)
{
    __shared__ __align__(16) float4 sA4[64];   // prescaled A rows i0..i0+3
    __shared__ float sWu2[64];                 // 2*log2e*wu
    __shared__ float sSwuL;
    __shared__ int   mtype_s;

    const int tid = threadIdx.x;
    const int i0  = (blockIdx.x >> 1) * 4;
    const int j0  = (blockIdx.x & 1) * 640;

    if (tid < 64) {
        const unsigned int* mw = (const unsigned int*)maskp;
        unsigned int w = mw[tid];
        unsigned long long notf = __ballot(w != 0u && w != 0x3F800000u);
        unsigned long long gt1  = __ballot(w > 1u);
        if (tid == 0) mtype_s = (notf == 0ull) ? 2 : ((gt1 == 0ull) ? 1 : 0);
        float wu = Wu[tid];
        float4 p;
        p.x = Ap[(size_t)(i0 + 0) * 64 + tid];
        p.y = Ap[(size_t)(i0 + 1) * 64 + tid];
        p.z = Ap[(size_t)(i0 + 2) * 64 + tid];
        p.w = Ap[(size_t)(i0 + 3) * 64 + tid];
        sA4[tid]  = p;
        sWu2[tid] = wu * (2.0f * LOG2E);
        float s = wu;
        #pragma unroll
        for (int off = 32; off > 0; off >>= 1) s += __shfl_down(s, off);
        if (tid == 0) sSwuL = s * LOG2E;
    }
    __syncthreads();

    const int j2 = j0 + tid * 2;
    float2 acc[4];
    #pragma unroll
    for (int i = 0; i < 4; i++) acc[i] = make_float2(0.f, 0.f);

    #pragma unroll 4
    for (int e = 0; e < 64; e++) {
        float2 b = *(const float2*)(BvT + (size_t)e * NJ + j2);
        float4 a = sA4[e];
        float w2 = sWu2[e];
        float t, r;
        t = a.x + b.x; r = __builtin_amdgcn_rcpf(exp2_fast(t) + 1.f); acc[0].x = fmaf(w2, r, acc[0].x);
        t = a.x + b.y; r = __builtin_amdgcn_rcpf(exp2_fast(t) + 1.f); acc[0].y = fmaf(w2, r, acc[0].y);
        t = a.y + b.x; r = __builtin_amdgcn_rcpf(exp2_fast(t) + 1.f); acc[1].x = fmaf(w2, r, acc[1].x);
        t = a.y + b.y; r = __builtin_amdgcn_rcpf(exp2_fast(t) + 1.f); acc[1].y = fmaf(w2, r, acc[1].y);
        t = a.z + b.x; r = __builtin_amdgcn_rcpf(exp2_fast(t) + 1.f); acc[2].x = fmaf(w2, r, acc[2].x);
        t = a.z + b.y; r = __builtin_amdgcn_rcpf(exp2_fast(t) + 1.f); acc[2].y = fmaf(w2, r, acc[2].y);
        t = a.w + b.x; r = __builtin_amdgcn_rcpf(exp2_fast(t) + 1.f); acc[3].x = fmaf(w2, r, acc[3].x);
        t = a.w + b.y; r = __builtin_amdgcn_rcpf(exp2_fast(t) + 1.f); acc[3].y = fmaf(w2, r, acc[3].y);
    }

    const float SwuL = sSwuL;
    const int mtype = mtype_s;
    const unsigned char* m8  = (const unsigned char*)maskp;
    const unsigned int*  m32 = (const unsigned int*)maskp;
    const float*         mfl = (const float*)maskp;

    #pragma unroll
    for (int i = 0; i < 4; i++) {
        size_t off = (size_t)(i0 + i) * NJ + j2;
        bool b0, b1;
        if (mtype == 0) {
            unsigned short m = *(const unsigned short*)(m8 + off);
            b0 = (m & 0xffu) != 0; b1 = (m >> 8) != 0;
        } else if (mtype == 1) {
            uint2 m = *(const uint2*)(m32 + off);
            b0 = m.x != 0u; b1 = m.y != 0u;
        } else {
            float2 m = *(const float2*)(mfl + off);
            b0 = m.x != 0.f; b1 = m.y != 0.f;
        }
        float e0 = b0 ? exp2_fast(SwuL - acc[i].x) : 0.f;
        float e1 = b1 ? exp2_fast(SwuL - acc[i].y) : 0.f;
        *(float2*)&sc[off] = make_float2(e0, e1);
    }
}

// ---- Kernel 3 (C): rowsum + context.  256 blocks x 256 thr, 4 rows each ----
__global__ __launch_bounds__(256) void ctx_kernel(
    const float* __restrict__ feat, const float* __restrict__ hid,
    const float* __restrict__ sc, float* __restrict__ ctx)
{
    __shared__ __align__(16) float sc_s[4][NJ];       // 20 KB
    __shared__ __align__(16) float red[4][16][64];    // 16 KB
    __shared__ float ssum_s[4];
    const int tid = threadIdx.x;
    const int i0  = blockIdx.x * 4;

    #pragma unroll
    for (int rep = 0; rep < 5; rep++) {
        int idx = tid + rep * 256;          // 0..1279
        int i   = idx / 320;
        int jq  = idx - i * 320;
        *(float4*)&sc_s[i][jq * 4] = *(const float4*)&sc[(size_t)(i0 + i) * NJ + jq * 4];
    }
    __syncthreads();
    {
        int i = tid >> 6, e = tid & 63;
        float s = 0.f;
        #pragma unroll
        for (int g = 0; g < 20; g++) s += sc_s[i][e + g * 64];
        #pragma unroll
        for (int off = 32; off > 0; off >>= 1) s += __shfl_down(s, off);
        if (e == 0) ssum_s[i] = (s == 0.f) ? 1.f : s;
    }

    const int jg = tid >> 4;              // 0..15
    const int e4 = (tid & 15) * 4;
    float4 c[4];
    #pragma unroll
    for (int i = 0; i < 4; i++) c[i] = make_float4(0.f, 0.f, 0.f, 0.f);
    for (int it = 0; it < 80; it++) {
        int j = it * 16 + jg;
        const float* fr = (j < NF) ? (feat + (size_t)j * 64)
                                   : (hid  + (size_t)(j - NF) * 64);
        float4 f = *(const float4*)(fr + e4);
        #pragma unroll
        for (int i = 0; i < 4; i++) {
            float w = sc_s[i][j];
            c[i].x += w*f.x; c[i].y += w*f.y; c[i].z += w*f.z; c[i].w += w*f.w;
        }
    }
    #pragma unroll
    for (int i = 0; i < 4; i++) *(float4*)&red[i][jg][e4] = c[i];
    __syncthreads();
    {
        int half = tid >> 6, e = tid & 63;
        float v = 0.f;
        #pragma unroll
        for (int g = 0; g < 16; g++) v += red[half][g][e];
        ctx[(size_t)(i0 + half) * 64 + e] = v / ssum_s[half];
    }
}

// ---- Kernel 4: out = values @ ctx.  128x64 tile, 8x8/thread, ksplit 8, atomics ----
__global__ __launch_bounds__(128) void out_mm_kernel(
    const float* __restrict__ values, const float* __restrict__ ctxp,
    float* __restrict__ out)
{
    __shared__ __align__(16) float vsT[64 * 128];   // [k][r^swz] 32 KB
    __shared__ __align__(16) float cs[64][64];      // 16 KB
    const int tid = threadIdx.x;
    const int rt  = blockIdx.x >> 3;     // 64 row tiles of 128
    const int kq  = blockIdx.x & 7;      // 8 K-slices of 128
    const int r0  = rt * 128;
    const int trg8 = (tid >> 3) * 8;     // 8 rows
    const int tc8  = (tid & 7) * 8;      // 8 cols

    float acc[8][8];
    #pragma unroll
    for (int a = 0; a < 8; a++)
        #pragma unroll
        for (int b = 0; b < 8; b++) acc[a][b] = 0.f;

    for (int kt = 0; kt < 2; kt++) {
        const int k0 = kq * 128 + kt * 64;
        __syncthreads();
        #pragma unroll
        for (int s = 0; s < 16; s++) {       // stage values transposed + swizzled
            int t  = tid + s * 128;          // 0..2047
            int r  = t >> 4;                 // 0..127
            int k4 = (t & 15) * 4;
            float4 g = *(const float4*)&values[(size_t)(r0 + r) * NF + k0 + k4];
            #pragma unroll
            for (int q = 0; q < 4; q++) {
                int k = k4 + q;
                int swz = ((k >> 2) & 3) << 3;
                float gv = (q == 0) ? g.x : (q == 1) ? g.y : (q == 2) ? g.z : g.w;
                vsT[k * 128 + (r ^ swz)] = gv;
            }
        }
        #pragma unroll
        for (int s = 0; s < 8; s++) {        // stage ctx tile
            int t  = tid + s * 128;          // 0..1023
            int kk = t >> 4;
            int c4 = (t & 15) * 4;
            *(float4*)&cs[kk][c4] = *(const float4*)&ctxp[(size_t)(k0 + kk) * ED + c4];
        }
        __syncthreads();
        #pragma unroll 4
        for (int k = 0; k < 64; k++) {
            int swz = ((k >> 2) & 3) << 3;
            int abase = k * 128 + (trg8 ^ swz);
            float4 a0 = *(const float4*)&vsT[abase];
            float4 a1 = *(const float4*)&vsT[abase + 4];
            float4 b0 = *(const float4*)&cs[k][tc8];
            float4 b1 = *(const float4*)&cs[k][tc8 + 4];
            float av[8] = {a0.x,a0.y,a0.z,a0.w,a1.x,a1.y,a1.z,a1.w};
            float bv[8] = {b0.x,b0.y,b0.z,b0.w,b1.x,b1.y,b1.z,b1.w};
            #pragma unroll
            for (int ri = 0; ri < 8; ri++)
                #pragma unroll
                for (int ci = 0; ci < 8; ci++)
                    acc[ri][ci] += av[ri] * bv[ci];
        }
    }
    #pragma unroll
    for (int ri = 0; ri < 8; ri++) {
        float* op = out + (size_t)(r0 + trg8 + ri) * ED + tc8;
        #pragma unroll
        for (int ci = 0; ci < 8; ci++)
            unsafeAtomicAdd(op + ci, acc[ri][ci]);
    }
}

extern "C" void kernel_launch(void* const* d_in, const int* in_sizes, int n_in,
                              void* d_out, int out_size, void* d_ws, size_t ws_size,
                              hipStream_t stream) {
    const float* values = (const float*)d_in[0];
    const float* feat   = (const float*)d_in[1];
    const float* hid    = (const float*)d_in[2];
    const float* Ww     = (const float*)d_in[3];
    const float* bw     = (const float*)d_in[4];
    const float* Wu     = (const float*)d_in[5];
    const void*  mask   = d_in[6];
    float* out = (float*)d_out;

    float* Ap  = (float*)d_ws;                 // 1024*64*4 = 256 KiB (prescaled)
    float* BvT = Ap + (size_t)NF * 64;         // 64*1280*4 = 320 KiB (prescaled)
    float* ctx = BvT + (size_t)ED * NJ;        // 1024*64*4 = 256 KiB
    float* sc  = ctx + (size_t)NF * 64;        // 1024*1280*4 = 5 MiB

    hipMemsetAsync(d_out, 0, (size_t)BATCH * ED * sizeof(float), stream);
    hipLaunchKernelGGL(prep_kernel, dim3(36), dim3(256), 0, stream,
                       feat, hid, Ww, bw, Ap, BvT);
    hipLaunchKernelGGL(score_kernel, dim3(512), dim3(320), 0, stream,
                       Wu, Ap, BvT, mask, sc);
    hipLaunchKernelGGL(ctx_kernel, dim3(256), dim3(256), 0, stream,
                       feat, hid, sc, ctx);
    hipLaunchKernelGGL(out_mm_kernel, dim3(512), dim3(128), 0, stream,
                       values, ctx, out);
}

// Round 7
// 153.637 us; speedup vs baseline: 1.7427x; 1.7427x over previous
//
#include <hip/hip_runtime.h>
#include <hip/hip_bf16.h>

#define NF   1024   // N features
#define NHID 256    // H hidden
#define NJ   1280   // N+H keys
#define ED   64     // E = HD = 64
#define BATCH 8192

#define K2E   2.8853900817779268f   // 2*log2(e)
#define LOG2E 1.4426950408889634f

__device__ __forceinline__ float exp2_fast(float x) {
    float r;
    asm volatile("v_exp_f32 %0, %1" : "=v"(r) : "v"(x));
    return r;
}

// ---- Kernel 1: Ap[i][e] = K2E*(feat@W1) ; BvT[e][j] = K2E*((full@W2)[j][e] + bw[e]) ----
__global__ __launch_bounds__(256) void prep_kernel(
    const float* __restrict__ feat, const float* __restrict__ hid,
    const float* __restrict__ Ww, const float* __restrict__ bw,
    float* __restrict__ Ap, float* __restrict__ BvT)
{
    __shared__ __align__(16) float in_s[64][64];
    __shared__ __align__(16) float tout[64][65];
    const int tid = threadIdx.x;
    const int b   = blockIdx.x;
    const bool isA = (b < 16);
    const int e  = tid & 63;
    const int wv = tid >> 6;

    const float* W = isA ? Ww : (Ww + 4096);
    float wcol[64];
    #pragma unroll
    for (int k = 0; k < 64; k++) wcol[k] = W[k * 64 + e];
    const float bias = isA ? 0.f : bw[e];

    const int bb = isA ? b : (b - 16);
    const float* src = isA ? (feat + (size_t)bb * 4096)
                     : (bb < 16 ? (feat + (size_t)bb * 4096)
                                : (hid + (size_t)(bb - 16) * 4096));
    #pragma unroll
    for (int s = 0; s < 4; s++)
        ((float4*)&in_s[0][0])[tid + s * 256] = ((const float4*)src)[tid + s * 256];
    __syncthreads();

    float acc[16];
    #pragma unroll
    for (int r = 0; r < 16; r++) acc[r] = bias;
    for (int k4 = 0; k4 < 64; k4 += 4) {
        #pragma unroll
        for (int r = 0; r < 16; r++) {
            float4 iv = *(const float4*)&in_s[wv * 16 + r][k4];
            acc[r] += iv.x*wcol[k4+0] + iv.y*wcol[k4+1] + iv.z*wcol[k4+2] + iv.w*wcol[k4+3];
        }
    }

    if (isA) {
        #pragma unroll
        for (int r = 0; r < 16; r++)
            Ap[(size_t)(b * 64 + wv * 16 + r) * 64 + e] = acc[r] * K2E;
    } else {
        #pragma unroll
        for (int r = 0; r < 16; r++) tout[wv * 16 + r][e] = acc[r] * K2E;
        __syncthreads();
        const int j0 = bb * 64;
        #pragma unroll
        for (int q = 0; q < 4; q++) {
            float4 v;
            v.x = tout[wv * 16 + q * 4 + 0][e];
            v.y = tout[wv * 16 + q * 4 + 1][e];
            v.z = tout[wv * 16 + q * 4 + 2][e];
            v.w = tout[wv * 16 + q * 4 + 3][e];
            *(float4*)&BvT[(size_t)e * NJ + j0 + wv * 16 + q * 4] = v;
        }
    }
}

// ---- Kernel 2 (S): masked exp-scores.  Block = 4 rows x 256 j.  Grid 1280 = 5 blk/CU ----
// 1 j per thread, 4 independent i-chains, coalesced scalar BvT loads, LDS 1.3 KB.
__global__ __launch_bounds__(256) void score_kernel(
    const float* __restrict__ Wu, const float* __restrict__ Ap,
    const float* __restrict__ BvT, const void* __restrict__ maskp,
    float* __restrict__ sc)
{
    __shared__ __align__(16) float4 sA4[64];   // prescaled A rows i0..i0+3
    __shared__ float sWu2[64];                 // 2*log2e*wu
    __shared__ float sSwuL;
    __shared__ int   mtype_s;

    const int tid = threadIdx.x;
    const int iq  = blockIdx.x / 5;
    const int jc  = blockIdx.x - iq * 5;
    const int i0  = iq * 4;
    const int j   = jc * 256 + tid;

    if (tid < 64) {
        const unsigned int* mw = (const unsigned int*)maskp;
        unsigned int w = mw[tid];
        unsigned long long notf = __ballot(w != 0u && w != 0x3F800000u);
        unsigned long long gt1  = __ballot(w > 1u);
        if (tid == 0) mtype_s = (notf == 0ull) ? 2 : ((gt1 == 0ull) ? 1 : 0);
        float wu = Wu[tid];
        float4 p;
        p.x = Ap[(size_t)(i0 + 0) * 64 + tid];
        p.y = Ap[(size_t)(i0 + 1) * 64 + tid];
        p.z = Ap[(size_t)(i0 + 2) * 64 + tid];
        p.w = Ap[(size_t)(i0 + 3) * 64 + tid];
        sA4[tid]  = p;
        sWu2[tid] = wu * (2.0f * LOG2E);
        float s = wu;
        #pragma unroll
        for (int off = 32; off > 0; off >>= 1) s += __shfl_down(s, off);
        if (tid == 0) sSwuL = s * LOG2E;
    }
    __syncthreads();

    const float* bp = BvT + j;
    float acc0 = 0.f, acc1 = 0.f, acc2 = 0.f, acc3 = 0.f;
    #pragma unroll 8
    for (int e = 0; e < 64; e++) {
        float b  = bp[(size_t)e * NJ];       // coalesced across lanes
        float4 a = sA4[e];                   // LDS broadcast
        float w2 = sWu2[e];
        float t, r;
        t = a.x + b; r = __builtin_amdgcn_rcpf(exp2_fast(t) + 1.f); acc0 = fmaf(w2, r, acc0);
        t = a.y + b; r = __builtin_amdgcn_rcpf(exp2_fast(t) + 1.f); acc1 = fmaf(w2, r, acc1);
        t = a.z + b; r = __builtin_amdgcn_rcpf(exp2_fast(t) + 1.f); acc2 = fmaf(w2, r, acc2);
        t = a.w + b; r = __builtin_amdgcn_rcpf(exp2_fast(t) + 1.f); acc3 = fmaf(w2, r, acc3);
    }

    const float SwuL = sSwuL;
    const int mtype = mtype_s;
    const unsigned char* m8  = (const unsigned char*)maskp;
    const unsigned int*  m32 = (const unsigned int*)maskp;
    const float*         mfl = (const float*)maskp;
    float av[4] = {acc0, acc1, acc2, acc3};
    #pragma unroll
    for (int i = 0; i < 4; i++) {
        size_t off = (size_t)(i0 + i) * NJ + j;
        bool bm;
        if (mtype == 0)      bm = m8[off]  != 0;
        else if (mtype == 1) bm = m32[off] != 0u;
        else                 bm = mfl[off] != 0.f;
        sc[off] = bm ? exp2_fast(SwuL - av[i]) : 0.f;
    }
}

// ---- Kernel 3 (C): rowsum + context.  256 blocks x 256 thr, 4 rows each ----
__global__ __launch_bounds__(256) void ctx_kernel(
    const float* __restrict__ feat, const float* __restrict__ hid,
    const float* __restrict__ sc, float* __restrict__ ctx)
{
    __shared__ __align__(16) float sc_s[4][NJ];       // 20 KB
    __shared__ __align__(16) float red[4][16][64];    // 16 KB
    __shared__ float ssum_s[4];
    const int tid = threadIdx.x;
    const int i0  = blockIdx.x * 4;

    #pragma unroll
    for (int rep = 0; rep < 5; rep++) {
        int idx = tid + rep * 256;          // 0..1279
        int i   = idx / 320;
        int jq  = idx - i * 320;
        *(float4*)&sc_s[i][jq * 4] = *(const float4*)&sc[(size_t)(i0 + i) * NJ + jq * 4];
    }
    __syncthreads();
    {
        int i = tid >> 6, e = tid & 63;
        float s = 0.f;
        #pragma unroll
        for (int g = 0; g < 20; g++) s += sc_s[i][e + g * 64];
        #pragma unroll
        for (int off = 32; off > 0; off >>= 1) s += __shfl_down(s, off);
        if (e == 0) ssum_s[i] = (s == 0.f) ? 1.f : s;
    }

    const int jg = tid >> 4;              // 0..15
    const int e4 = (tid & 15) * 4;
    float4 c[4];
    #pragma unroll
    for (int i = 0; i < 4; i++) c[i] = make_float4(0.f, 0.f, 0.f, 0.f);
    for (int it = 0; it < 80; it++) {
        int j = it * 16 + jg;
        const float* fr = (j < NF) ? (feat + (size_t)j * 64)
                                   : (hid  + (size_t)(j - NF) * 64);
        float4 f = *(const float4*)(fr + e4);
        #pragma unroll
        for (int i = 0; i < 4; i++) {
            float w = sc_s[i][j];
            c[i].x += w*f.x; c[i].y += w*f.y; c[i].z += w*f.z; c[i].w += w*f.w;
        }
    }
    #pragma unroll
    for (int i = 0; i < 4; i++) *(float4*)&red[i][jg][e4] = c[i];
    __syncthreads();
    {
        int half = tid >> 6, e = tid & 63;
        float v = 0.f;
        #pragma unroll
        for (int g = 0; g < 16; g++) v += red[half][g][e];
        ctx[(size_t)(i0 + half) * 64 + e] = v / ssum_s[half];
    }
}

// ---- Kernel 4: out = values @ ctx.  64x64 tile, 4x4/thread, ksplit 8 (round-4 layout,
//      measured conflict-free).  mode0: partials; mode1: atomics (fallback) ----
__global__ __launch_bounds__(256) void out_mm_kernel(
    const float* __restrict__ values, const float* __restrict__ ctxp,
    float* __restrict__ dst, int atomic_mode)
{
    __shared__ __align__(16) float vsT[64 * 64];
    __shared__ __align__(16) float cs[64][64];
    const int tid = threadIdx.x;
    const int rt  = blockIdx.x >> 3;     // 128 row tiles
    const int kq  = blockIdx.x & 7;      // 8 K-slices of 128
    const int r0  = rt * 64;
    const int tr  = tid >> 4;
    const int tc4 = (tid & 15) * 4;

    float acc[4][4];
    #pragma unroll
    for (int a = 0; a < 4; a++)
        #pragma unroll
        for (int b = 0; b < 4; b++) acc[a][b] = 0.f;

    for (int ch = 0; ch < 2; ch++) {
        const int k0 = kq * 128 + ch * 64;
        __syncthreads();
        #pragma unroll
        for (int s = 0; s < 4; s++) {           // stage V transposed+swizzled (2-way max)
            int t   = tid + s * 256;
            int r   = t >> 4;
            int kk4 = (t & 15) * 4;
            float4 g = *(const float4*)&values[(size_t)(r0 + r) * NF + k0 + kk4];
            int p  = (((r >> 2) + (t & 15)) & 15) * 4 + (r & 3);
            vsT[(kk4 + 0) * 64 + p] = g.x;
            vsT[(kk4 + 1) * 64 + p] = g.y;
            vsT[(kk4 + 2) * 64 + p] = g.z;
            vsT[(kk4 + 3) * 64 + p] = g.w;
        }
        #pragma unroll
        for (int s = 0; s < 4; s++) {           // stage ctx tile
            int t  = tid + s * 256;
            int kk = t >> 4;
            int c4 = (t & 15) * 4;
            *(float4*)&cs[kk][c4] = *(const float4*)&ctxp[(size_t)(k0 + kk) * ED + c4];
        }
        __syncthreads();
        #pragma unroll 8
        for (int k = 0; k < 64; k++) {
            float4 av = *(const float4*)&vsT[k * 64 + (((tr + (k >> 2)) & 15) << 2)];
            float4 bv = *(const float4*)&cs[k][tc4];
            acc[0][0] += av.x*bv.x; acc[0][1] += av.x*bv.y; acc[0][2] += av.x*bv.z; acc[0][3] += av.x*bv.w;
            acc[1][0] += av.y*bv.x; acc[1][1] += av.y*bv.y; acc[1][2] += av.y*bv.z; acc[1][3] += av.y*bv.w;
            acc[2][0] += av.z*bv.x; acc[2][1] += av.z*bv.y; acc[2][2] += av.z*bv.z; acc[2][3] += av.z*bv.w;
            acc[3][0] += av.w*bv.x; acc[3][1] += av.w*bv.y; acc[3][2] += av.w*bv.z; acc[3][3] += av.w*bv.w;
        }
    }
    if (atomic_mode) {
        #pragma unroll
        for (int i2 = 0; i2 < 4; i2++) {
            int r = r0 + tr * 4 + i2;
            float* op = dst + (size_t)r * ED + tc4;
            unsafeAtomicAdd(op + 0, acc[i2][0]);
            unsafeAtomicAdd(op + 1, acc[i2][1]);
            unsafeAtomicAdd(op + 2, acc[i2][2]);
            unsafeAtomicAdd(op + 3, acc[i2][3]);
        }
    } else {
        #pragma unroll
        for (int i2 = 0; i2 < 4; i2++) {
            int r = r0 + tr * 4 + i2;
            float* op = dst + ((size_t)kq * BATCH + r) * ED + tc4;
            *(float4*)op = make_float4(acc[i2][0], acc[i2][1], acc[i2][2], acc[i2][3]);
        }
    }
}

// ---- Kernel 5: out = sum of 8 partials (float4) ----
__global__ __launch_bounds__(256) void reduce8_kernel(
    const float* __restrict__ part, float* __restrict__ out)
{
    const size_t S = (size_t)BATCH * ED / 4;
    size_t idx = (size_t)blockIdx.x * 256 + threadIdx.x;
    const float4* p = (const float4*)part;
    float4 r = {0.f, 0.f, 0.f, 0.f};
    #pragma unroll
    for (int q = 0; q < 8; q++) {
        float4 a = p[idx + (size_t)q * S];
        r.x += a.x; r.y += a.y; r.z += a.z; r.w += a.w;
    }
    ((float4*)out)[idx] = r;
}

extern "C" void kernel_launch(void* const* d_in, const int* in_sizes, int n_in,
                              void* d_out, int out_size, void* d_ws, size_t ws_size,
                              hipStream_t stream) {
    const float* values = (const float*)d_in[0];
    const float* feat   = (const float*)d_in[1];
    const float* hid    = (const float*)d_in[2];
    const float* Ww     = (const float*)d_in[3];
    const float* bw     = (const float*)d_in[4];
    const float* Wu     = (const float*)d_in[5];
    const void*  mask   = d_in[6];
    float* out = (float*)d_out;

    float* Ap  = (float*)d_ws;                 // 1024*64*4   = 256 KiB (prescaled)
    float* BvT = Ap + (size_t)NF * 64;         // 64*1280*4   = 320 KiB (prescaled)
    float* ctx = BvT + (size_t)ED * NJ;        // 1024*64*4   = 256 KiB
    float* sc  = ctx + (size_t)NF * 64;        // 1024*1280*4 = 5 MiB
    float* part = sc + (size_t)NF * NJ;        // 8*8192*64*4 = 16 MiB
    const size_t need = ((size_t)NF*64 + (size_t)ED*NJ + (size_t)NF*64
                         + (size_t)NF*NJ + (size_t)8*BATCH*ED) * sizeof(float);
    const bool wsmode = ws_size >= need;

    hipLaunchKernelGGL(prep_kernel, dim3(36), dim3(256), 0, stream,
                       feat, hid, Ww, bw, Ap, BvT);
    hipLaunchKernelGGL(score_kernel, dim3(1280), dim3(256), 0, stream,
                       Wu, Ap, BvT, mask, sc);
    hipLaunchKernelGGL(ctx_kernel, dim3(256), dim3(256), 0, stream,
                       feat, hid, sc, ctx);
    if (wsmode) {
        hipLaunchKernelGGL(out_mm_kernel, dim3(1024), dim3(256), 0, stream,
                           values, ctx, part, 0);
        hipLaunchKernelGGL(reduce8_kernel, dim3(BATCH * ED / 4 / 256), dim3(256), 0, stream,
                           part, out);
    } else {
        hipMemsetAsync(d_out, 0, (size_t)BATCH * ED * sizeof(float), stream);
        hipLaunchKernelGGL(out_mm_kernel, dim3(1024), dim3(256), 0, stream,
                           values, ctx, out, 1);
    }
}

// Round 10
// 146.085 us; speedup vs baseline: 1.8327x; 1.0517x over previous
//
#include <hip/hip_runtime.h>
#include <hip/hip_bf16.h>

#define NF   1024   // N features
#define NHID 256    // H hidden
#define NJ   1280   // N+H keys
#define ED   64     // E = HD = 64
#define BATCH 8192

#define K2E   2.8853900817779268f   // 2*log2(e)
#define LOG2E 1.4426950408889634f

__device__ __forceinline__ float exp2_fast(float x) {
    float r;
    asm("v_exp_f32 %0, %1" : "=v"(r) : "v"(x));
    return r;
}

// ---- Kernel 1: Ap[i][e] = K2E*(feat@W1) ; BvT[e][j] = K2E*((full@W2)[j][e]+bw[e]) ;
//      swu[0] = LOG2E * sum(Wu) ----
__global__ __launch_bounds__(256) void prep_kernel(
    const float* __restrict__ feat, const float* __restrict__ hid,
    const float* __restrict__ Ww, const float* __restrict__ bw,
    const float* __restrict__ Wu,
    float* __restrict__ Ap, float* __restrict__ BvT, float* __restrict__ swu)
{
    __shared__ __align__(16) float in_s[64][64];
    __shared__ __align__(16) float tout[64][65];
    const int tid = threadIdx.x;
    const int b   = blockIdx.x;
    const bool isA = (b < 16);
    const int e  = tid & 63;
    const int wv = tid >> 6;

    if (b == 0 && tid < 64) {           // Swu side-compute (first wave)
        float s = Wu[tid];
        #pragma unroll
        for (int off = 32; off > 0; off >>= 1) s += __shfl_down(s, off);
        if (tid == 0) swu[0] = s * LOG2E;
    }

    const float* W = isA ? Ww : (Ww + 4096);
    float wcol[64];
    #pragma unroll
    for (int k = 0; k < 64; k++) wcol[k] = W[k * 64 + e];
    const float bias = isA ? 0.f : bw[e];

    const int bb = isA ? b : (b - 16);
    const float* src = isA ? (feat + (size_t)bb * 4096)
                     : (bb < 16 ? (feat + (size_t)bb * 4096)
                                : (hid + (size_t)(bb - 16) * 4096));
    #pragma unroll
    for (int s = 0; s < 4; s++)
        ((float4*)&in_s[0][0])[tid + s * 256] = ((const float4*)src)[tid + s * 256];
    __syncthreads();

    float acc[16];
    #pragma unroll
    for (int r = 0; r < 16; r++) acc[r] = bias;
    for (int k4 = 0; k4 < 64; k4 += 4) {
        #pragma unroll
        for (int r = 0; r < 16; r++) {
            float4 iv = *(const float4*)&in_s[wv * 16 + r][k4];
            acc[r] += iv.x*wcol[k4+0] + iv.y*wcol[k4+1] + iv.z*wcol[k4+2] + iv.w*wcol[k4+3];
        }
    }

    if (isA) {
        #pragma unroll
        for (int r = 0; r < 16; r++)
            Ap[(size_t)(b * 64 + wv * 16 + r) * 64 + e] = acc[r] * K2E;
    } else {
        #pragma unroll
        for (int r = 0; r < 16; r++) tout[wv * 16 + r][e] = acc[r] * K2E;
        __syncthreads();
        const int j0 = bb * 64;
        #pragma unroll
        for (int q = 0; q < 4; q++) {
            float4 v;
            v.x = tout[wv * 16 + q * 4 + 0][e];
            v.y = tout[wv * 16 + q * 4 + 1][e];
            v.z = tout[wv * 16 + q * 4 + 2][e];
            v.w = tout[wv * 16 + q * 4 + 3][e];
            *(float4*)&BvT[(size_t)e * NJ + j0 + wv * 16 + q * 4] = v;
        }
    }
}

// ---- Kernel 2 (S): masked exp-scores.  Block = 4 rows x 256 j, grid 1280 ----
// A/Wu read via block-uniform addresses -> SMEM s_load (no LDS in inner loop).
__global__ __launch_bounds__(256) void score_kernel(
    const float* __restrict__ Wu, const float* __restrict__ Ap,
    const float* __restrict__ BvT, const float* __restrict__ swu,
    const void* __restrict__ maskp, float* __restrict__ sc)
{
    __shared__ int mtype_s;
    const int tid = threadIdx.x;
    const int iq  = blockIdx.x / 5;
    const int jc  = blockIdx.x - iq * 5;
    const int i0  = iq * 4;
    const int j   = jc * 256 + tid;

    if (tid < 64) {
        const unsigned int* mw = (const unsigned int*)maskp;
        unsigned int w = mw[tid];
        unsigned long long notf = __ballot(w != 0u && w != 0x3F800000u);
        unsigned long long gt1  = __ballot(w > 1u);
        if (tid == 0) mtype_s = (notf == 0ull) ? 2 : ((gt1 == 0ull) ? 1 : 0);
    }
    __syncthreads();

    const float* a0p = Ap + (size_t)(i0 + 0) * 64;   // block-uniform bases
    const float* a1p = Ap + (size_t)(i0 + 1) * 64;
    const float* a2p = Ap + (size_t)(i0 + 2) * 64;
    const float* a3p = Ap + (size_t)(i0 + 3) * 64;
    const float* bp  = BvT + j;

    float acc0 = 0.f, acc1 = 0.f, acc2 = 0.f, acc3 = 0.f;
    #pragma unroll 8
    for (int e = 0; e < 64; e++) {
        float b  = bp[(size_t)e * NJ];   // coalesced vector load
        float wu = Wu[e];                // uniform -> SGPR
        float t, r;
        t = a0p[e] + b; r = __builtin_amdgcn_rcpf(exp2_fast(t) + 1.f); acc0 = fmaf(wu, r, acc0);
        t = a1p[e] + b; r = __builtin_amdgcn_rcpf(exp2_fast(t) + 1.f); acc1 = fmaf(wu, r, acc1);
        t = a2p[e] + b; r = __builtin_amdgcn_rcpf(exp2_fast(t) + 1.f); acc2 = fmaf(wu, r, acc2);
        t = a3p[e] + b; r = __builtin_amdgcn_rcpf(exp2_fast(t) + 1.f); acc3 = fmaf(wu, r, acc3);
    }

    const float SwuL = swu[0];           // uniform
    const int mtype = mtype_s;
    const unsigned char* m8  = (const unsigned char*)maskp;
    const unsigned int*  m32 = (const unsigned int*)maskp;
    const float*         mfl = (const float*)maskp;
    float av[4] = {acc0, acc1, acc2, acc3};
    #pragma unroll
    for (int i = 0; i < 4; i++) {
        size_t off = (size_t)(i0 + i) * NJ + j;
        bool bm;
        if (mtype == 0)      bm = m8[off]  != 0;
        else if (mtype == 1) bm = m32[off] != 0u;
        else                 bm = mfl[off] != 0.f;
        sc[off] = bm ? exp2_fast(fmaf(-K2E, av[i], SwuL)) : 0.f;
    }
}

// ---- Kernel 3 (C): rowsum + context.  512 blocks x 256 thr, 2 rows each ----
__global__ __launch_bounds__(256) void ctx_kernel(
    const float* __restrict__ feat, const float* __restrict__ hid,
    const float* __restrict__ sc, float* __restrict__ ctx)
{
    __shared__ __align__(16) float sc_s[2][NJ];       // 10 KB
    __shared__ __align__(16) float red[2][16][64];    // 8 KB
    __shared__ float ssum_s[2];
    const int tid = threadIdx.x;
    const int i0  = blockIdx.x * 2;

    #pragma unroll
    for (int rep = 0; rep < 3; rep++) {     // 640 float4 slots, 256 thr -> 3 reps
        int idx = tid + rep * 256;          // 0..767
        if (idx < 640) {
            int i  = idx / 320;
            int jq = idx - i * 320;
            *(float4*)&sc_s[i][jq * 4] = *(const float4*)&sc[(size_t)(i0 + i) * NJ + jq * 4];
        }
    }
    __syncthreads();
    if (tid < 128) {
        int i = tid >> 6, e = tid & 63;
        float s = 0.f;
        #pragma unroll
        for (int g = 0; g < 20; g++) s += sc_s[i][e + g * 64];
        #pragma unroll
        for (int off = 32; off > 0; off >>= 1) s += __shfl_down(s, off);
        if (e == 0) ssum_s[i] = (s == 0.f) ? 1.f : s;
    }

    const int jg = tid >> 4;              // 0..15
    const int e4 = (tid & 15) * 4;
    float4 c0 = {0.f,0.f,0.f,0.f}, c1 = {0.f,0.f,0.f,0.f};
    for (int it = 0; it < 80; it++) {
        int j = it * 16 + jg;
        const float* fr = (j < NF) ? (feat + (size_t)j * 64)
                                   : (hid  + (size_t)(j - NF) * 64);
        float4 f = *(const float4*)(fr + e4);
        float w0 = sc_s[0][j], w1 = sc_s[1][j];
        c0.x += w0*f.x; c0.y += w0*f.y; c0.z += w0*f.z; c0.w += w0*f.w;
        c1.x += w1*f.x; c1.y += w1*f.y; c1.z += w1*f.z; c1.w += w1*f.w;
    }
    *(float4*)&red[0][jg][e4] = c0;
    *(float4*)&red[1][jg][e4] = c1;
    __syncthreads();
    if (tid < 128) {
        int half = tid >> 6, e = tid & 63;
        float v = 0.f;
        #pragma unroll
        for (int g = 0; g < 16; g++) v += red[half][g][e];
        ctx[(size_t)(i0 + half) * 64 + e] = v / ssum_s[half];
    }
}

// ---- Kernel 4: out = values @ ctx.  64x64 tile, 4x4/thread, ksplit 8 (conflict-free) ----
__global__ __launch_bounds__(256) void out_mm_kernel(
    const float* __restrict__ values, const float* __restrict__ ctxp,
    float* __restrict__ dst, int atomic_mode)
{
    __shared__ __align__(16) float vsT[64 * 64];
    __shared__ __align__(16) float cs[64][64];
    const int tid = threadIdx.x;
    const int rt  = blockIdx.x >> 3;     // 128 row tiles
    const int kq  = blockIdx.x & 7;      // 8 K-slices of 128
    const int r0  = rt * 64;
    const int tr  = tid >> 4;
    const int tc4 = (tid & 15) * 4;

    float acc[4][4];
    #pragma unroll
    for (int a = 0; a < 4; a++)
        #pragma unroll
        for (int b = 0; b < 4; b++) acc[a][b] = 0.f;

    for (int ch = 0; ch < 2; ch++) {
        const int k0 = kq * 128 + ch * 64;
        __syncthreads();
        #pragma unroll
        for (int s = 0; s < 4; s++) {           // stage V transposed+swizzled
            int t   = tid + s * 256;
            int r   = t >> 4;
            int kk4 = (t & 15) * 4;
            float4 g = *(const float4*)&values[(size_t)(r0 + r) * NF + k0 + kk4];
            int p  = (((r >> 2) + (t & 15)) & 15) * 4 + (r & 3);
            vsT[(kk4 + 0) * 64 + p] = g.x;
            vsT[(kk4 + 1) * 64 + p] = g.y;
            vsT[(kk4 + 2) * 64 + p] = g.z;
            vsT[(kk4 + 3) * 64 + p] = g.w;
        }
        #pragma unroll
        for (int s = 0; s < 4; s++) {           // stage ctx tile
            int t  = tid + s * 256;
            int kk = t >> 4;
            int c4 = (t & 15) * 4;
            *(float4*)&cs[kk][c4] = *(const float4*)&ctxp[(size_t)(k0 + kk) * ED + c4];
        }
        __syncthreads();
        #pragma unroll 8
        for (int k = 0; k < 64; k++) {
            float4 av = *(const float4*)&vsT[k * 64 + (((tr + (k >> 2)) & 15) << 2)];
            float4 bv = *(const float4*)&cs[k][tc4];
            acc[0][0] += av.x*bv.x; acc[0][1] += av.x*bv.y; acc[0][2] += av.x*bv.z; acc[0][3] += av.x*bv.w;
            acc[1][0] += av.y*bv.x; acc[1][1] += av.y*bv.y; acc[1][2] += av.y*bv.z; acc[1][3] += av.y*bv.w;
            acc[2][0] += av.z*bv.x; acc[2][1] += av.z*bv.y; acc[2][2] += av.z*bv.z; acc[2][3] += av.z*bv.w;
            acc[3][0] += av.w*bv.x; acc[3][1] += av.w*bv.y; acc[3][2] += av.w*bv.z; acc[3][3] += av.w*bv.w;
        }
    }
    if (atomic_mode) {
        #pragma unroll
        for (int i2 = 0; i2 < 4; i2++) {
            int r = r0 + tr * 4 + i2;
            float* op = dst + (size_t)r * ED + tc4;
            unsafeAtomicAdd(op + 0, acc[i2][0]);
            unsafeAtomicAdd(op + 1, acc[i2][1]);
            unsafeAtomicAdd(op + 2, acc[i2][2]);
            unsafeAtomicAdd(op + 3, acc[i2][3]);
        }
    } else {
        #pragma unroll
        for (int i2 = 0; i2 < 4; i2++) {
            int r = r0 + tr * 4 + i2;
            float* op = dst + ((size_t)kq * BATCH + r) * ED + tc4;
            *(float4*)op = make_float4(acc[i2][0], acc[i2][1], acc[i2][2], acc[i2][3]);
        }
    }
}

// ---- Kernel 5: out = sum of 8 partials (float4) ----
__global__ __launch_bounds__(256) void reduce8_kernel(
    const float* __restrict__ part, float* __restrict__ out)
{
    const size_t S = (size_t)BATCH * ED / 4;
    size_t idx = (size_t)blockIdx.x * 256 + threadIdx.x;
    const float4* p = (const float4*)part;
    float4 r = {0.f, 0.f, 0.f, 0.f};
    #pragma unroll
    for (int q = 0; q < 8; q++) {
        float4 a = p[idx + (size_t)q * S];
        r.x += a.x; r.y += a.y; r.z += a.z; r.w += a.w;
    }
    ((float4*)out)[idx] = r;
}

extern "C" void kernel_launch(void* const* d_in, const int* in_sizes, int n_in,
                              void* d_out, int out_size, void* d_ws, size_t ws_size,
                              hipStream_t stream) {
    const float* values = (const float*)d_in[0];
    const float* feat   = (const float*)d_in[1];
    const float* hid    = (const float*)d_in[2];
    const float* Ww     = (const float*)d_in[3];
    const float* bw     = (const float*)d_in[4];
    const float* Wu     = (const float*)d_in[5];
    const void*  mask   = d_in[6];
    float* out = (float*)d_out;

    float* Ap   = (float*)d_ws;                 // 1024*64*4   = 256 KiB (prescaled)
    float* BvT  = Ap + (size_t)NF * 64;         // 64*1280*4   = 320 KiB (prescaled)
    float* ctx  = BvT + (size_t)ED * NJ;        // 1024*64*4   = 256 KiB
    float* swu  = ctx + (size_t)NF * 64;        // 64 floats
    float* sc   = swu + 64;                     // 1024*1280*4 = 5 MiB
    float* part = sc + (size_t)NF * NJ;         // 8*8192*64*4 = 16 MiB
    const size_t need = ((size_t)NF*64 + (size_t)ED*NJ + (size_t)NF*64 + 64
                         + (size_t)NF*NJ + (size_t)8*BATCH*ED) * sizeof(float);
    const bool wsmode = ws_size >= need;

    hipLaunchKernelGGL(prep_kernel, dim3(36), dim3(256), 0, stream,
                       feat, hid, Ww, bw, Wu, Ap, BvT, swu);
    hipLaunchKernelGGL(score_kernel, dim3(1280), dim3(256), 0, stream,
                       Wu, Ap, BvT, swu, mask, sc);
    hipLaunchKernelGGL(ctx_kernel, dim3(512), dim3(256), 0, stream,
                       feat, hid, sc, ctx);
    if (wsmode) {
        hipLaunchKernelGGL(out_mm_kernel, dim3(1024), dim3(256), 0, stream,
                           values, ctx, part, 0);
        hipLaunchKernelGGL(reduce8_kernel, dim3(BATCH * ED / 4 / 256), dim3(256), 0, stream,
                           part, out);
    } else {
        hipMemsetAsync(d_out, 0, (size_t)BATCH * ED * sizeof(float), stream);
        hipLaunchKernelGGL(out_mm_kernel, dim3(1024), dim3(256), 0, stream,
                           values, ctx, out, 1);
    }
}